// Round 5
// baseline (694.807 us; speedup 1.0000x reference)
//
#include <hip/hip_runtime.h>

#define N_NODES 100000
#define N_EDGES 3200000
#define D 128

#define K1C    782        // coarse buckets: bucket = dst >> 7 (128 nodes each)
#define CHUNK  2048       // edges per partition block
#define NCHUNK 1563       // ceil(N_EDGES / CHUNK)
#define RCH    6144       // records per sort_reduce LDS chunk (mean 4096, +32 sigma)

// ---------------------------------------------------------------------------
// Workspace layout (bytes); total ~51.3 MB (ws >= 78 MB proven in round 2).
// ---------------------------------------------------------------------------
static const size_t OFF_SB    = 0;           // S bf16 packed: N*64 uints = 25,600,000
static const size_t OFF_REC   = 25600000;    // E int2 (coarse-partitioned)
static const size_t OFF_GHIST = 51200000;
static const size_t OFF_BOFFS = 51204096;
static const size_t OFF_GCUR  = 51208192;

typedef __attribute__((ext_vector_type(8))) short bf16x8;
typedef __attribute__((ext_vector_type(4))) float f32x4;

__device__ __forceinline__ unsigned short f2bf(float f) {
    unsigned u = __float_as_uint(f);
    return (unsigned short)((u + 0x7FFFu + ((u >> 16) & 1u)) >> 16);   // RNE
}

// ---------------------------------------------------------------------------
// S = X @ W via MFMA (bf16 in, fp32 acc, bf16 out, row-major packed pairs).
// Block = 128 nodes x 128 feats. B-fragments pre-packed in LDS (conflict-free
// contiguous b128 reads). A-fragments loaded directly from global fp32
// (each X element used exactly once). Epilogue transposes C-layout ->
// row-major via per-wave bf16 LDS staging, then coalesced dword stores.
// ---------------------------------------------------------------------------
__global__ __launch_bounds__(256) void gemm_mfma(const float* __restrict__ X,
                                                 const float* __restrict__ W,
                                                 unsigned* __restrict__ Sb) {
    __shared__ __align__(16) union {
        unsigned short wfrag[8][4][64][8];  // [ct][kt][lane][j], 16 B/lane entry = 32 KB
        unsigned       stage[4][32][68];    // [wave][row][dword] 128 bf16 + pad = 34 KB
    } u;

    const int t    = threadIdx.x;
    const int lane = t & 63;
    const int wave = t >> 6;
    const int quad = lane >> 4;
    const int li   = lane & 15;
    const int rowBase = blockIdx.x * 128;

    // ---- stage W[k][n] fp32 -> pre-packed bf16 B-fragments ----
    // B-frag for lane l: B[k = kt*32 + (l>>4)*8 + j][n = ct*16 + (l&15)]
    for (int i = t; i < D * D; i += 256) {
        int k = i >> 7, n = i & 127;
        u.wfrag[n >> 4][k >> 5][((k >> 3) & 3) * 16 + (n & 15)][k & 7] = f2bf(W[i]);
    }
    __syncthreads();

    f32x4 acc[2][8];
#pragma unroll
    for (int rt = 0; rt < 2; ++rt)
#pragma unroll
        for (int ct = 0; ct < 8; ++ct)
            acc[rt][ct] = (f32x4){0.f, 0.f, 0.f, 0.f};

#pragma unroll
    for (int kt = 0; kt < 4; ++kt) {
        // A-fragments: lane l holds A[m = rt*16 + li][k = kt*32 + quad*8 + j]
        bf16x8 a[2];
#pragma unroll
        for (int rt = 0; rt < 2; ++rt) {
            int row = rowBase + wave * 32 + rt * 16 + li;
            if (row >= N_NODES) row = N_NODES - 1;           // clamp; store masked
            const float* xp = X + (size_t)row * D + kt * 32 + quad * 8;
            float4 f0 = ((const float4*)xp)[0];
            float4 f1 = ((const float4*)xp)[1];
            bf16x8 av;
            av[0] = (short)f2bf(f0.x); av[1] = (short)f2bf(f0.y);
            av[2] = (short)f2bf(f0.z); av[3] = (short)f2bf(f0.w);
            av[4] = (short)f2bf(f1.x); av[5] = (short)f2bf(f1.y);
            av[6] = (short)f2bf(f1.z); av[7] = (short)f2bf(f1.w);
            a[rt] = av;
        }
#pragma unroll
        for (int ct = 0; ct < 8; ++ct) {
            bf16x8 b = *(const bf16x8*)&u.wfrag[ct][kt][lane][0];
            acc[0][ct] = __builtin_amdgcn_mfma_f32_16x16x32_bf16(a[0], b, acc[0][ct], 0, 0, 0);
            acc[1][ct] = __builtin_amdgcn_mfma_f32_16x16x32_bf16(a[1], b, acc[1][ct], 0, 0, 0);
        }
    }
    __syncthreads();   // all wfrag reads done before stage overwrites (union)

    // ---- epilogue: C-layout (col=lane&15, row=quad*4+reg) -> row-major bf16 ----
    unsigned short* sw = (unsigned short*)&u.stage[wave][0][0];  // 32 rows x 136 bf16
#pragma unroll
    for (int rt = 0; rt < 2; ++rt)
#pragma unroll
        for (int r = 0; r < 4; ++r) {
            int lrow = rt * 16 + quad * 4 + r;
#pragma unroll
            for (int ct = 0; ct < 8; ++ct)
                sw[lrow * 136 + ct * 16 + li] = f2bf(acc[rt][ct][r]);
        }
    // per-wave region, within-wave write->read: lgkmcnt handles ordering
    for (int lrow = 0; lrow < 32; ++lrow) {
        int node = rowBase + wave * 32 + lrow;
        if (node < N_NODES)
            Sb[(size_t)node * 64 + lane] = ((unsigned*)sw)[lrow * 68 + lane];
    }
}

// ---------------------------------------------------------------------------
// Coarse histogram over K1C buckets (LDS hist, one global flush per block)
// ---------------------------------------------------------------------------
__global__ __launch_bounds__(256) void hist_coarse(const int* __restrict__ edst,
                                                   int* __restrict__ ghist) {
    __shared__ int h[K1C];
    for (int i = threadIdx.x; i < K1C; i += 256) h[i] = 0;
    __syncthreads();
    for (int e = blockIdx.x * 256 + threadIdx.x; e < N_EDGES; e += gridDim.x * 256)
        atomicAdd(&h[edst[e] >> 7], 1);
    __syncthreads();
    for (int i = threadIdx.x; i < K1C; i += 256)
        if (h[i]) atomicAdd(&ghist[i], h[i]);
}

// Exclusive scan of K1C counters -> boffs[0..K1C], gcursor = copy of boffs.
__global__ __launch_bounds__(256) void scan_coarse(const int* __restrict__ ghist,
                                                   int* __restrict__ boffs,
                                                   int* __restrict__ gcursor) {
    __shared__ int sc[256];
    const int t = threadIdx.x;
    int v[4]; int s = 0;
#pragma unroll
    for (int j = 0; j < 4; ++j) {
        int idx = t * 4 + j;
        v[j] = (idx < K1C) ? ghist[idx] : 0;
        s += v[j];
    }
    sc[t] = s;
    __syncthreads();
    for (int off = 1; off < 256; off <<= 1) {
        int u = (t >= off) ? sc[t - off] : 0;
        __syncthreads();
        sc[t] += u;
        __syncthreads();
    }
    int run = (t == 0) ? 0 : sc[t - 1];
#pragma unroll
    for (int j = 0; j < 4; ++j) {
        int idx = t * 4 + j;
        if (idx < K1C) { boffs[idx] = run; gcursor[idx] = run; }
        run += v[j];
    }
    if (t == 255) boffs[K1C] = run;
}

// ---------------------------------------------------------------------------
// LDS-staged coarse partition (unchanged from round 4 — verified).
// rec.x = src | (dst&127)<<17 ; rec.y = val bits.
// ---------------------------------------------------------------------------
__global__ __launch_bounds__(256) void partition_edges(
        const int* __restrict__ esrc,
        const int* __restrict__ edst,
        const float* __restrict__ eval,
        int* __restrict__ gcursor,
        int2* __restrict__ rec_out) {
    __shared__ int  hist[K1C];
    __shared__ int  lofs[K1C];
    __shared__ int  gbase[K1C];
    __shared__ int  sc[256];
    __shared__ int2 staged[CHUNK];
    __shared__ unsigned short bkt[CHUNK];

    const int t   = threadIdx.x;
    const int e0  = blockIdx.x * CHUNK;
    const int cnt = min(CHUNK, N_EDGES - e0);

    for (int i = t; i < K1C; i += 256) hist[i] = 0;
    __syncthreads();

    int b[8], r[8], sv[8]; float vv[8];
#pragma unroll
    for (int j = 0; j < 8; ++j) {
        int idx = t + j * 256;
        if (idx < cnt) {
            int e = e0 + idx;
            int d = edst[e];
            sv[j] = esrc[e] | ((d & 127) << 17);
            vv[j] = eval[e];
            b[j]  = d >> 7;
            r[j]  = atomicAdd(&hist[b[j]], 1);
        } else b[j] = -1;
    }
    __syncthreads();

    int hv[4]; int hs = 0;
#pragma unroll
    for (int j = 0; j < 4; ++j) {
        int idx = t * 4 + j;
        hv[j] = (idx < K1C) ? hist[idx] : 0;
        hs += hv[j];
    }
    sc[t] = hs;
    __syncthreads();
    for (int off = 1; off < 256; off <<= 1) {
        int u = (t >= off) ? sc[t - off] : 0;
        __syncthreads();
        sc[t] += u;
        __syncthreads();
    }
    int run = (t == 0) ? 0 : sc[t - 1];
#pragma unroll
    for (int j = 0; j < 4; ++j) {
        int idx = t * 4 + j;
        if (idx < K1C) {
            lofs[idx]  = run;
            gbase[idx] = hv[j] ? atomicAdd(&gcursor[idx], hv[j]) : 0;
        }
        run += hv[j];
    }
    __syncthreads();

#pragma unroll
    for (int j = 0; j < 8; ++j) {
        if (b[j] >= 0) {
            int pos = lofs[b[j]] + r[j];
            staged[pos] = make_int2(sv[j], __float_as_int(vv[j]));
            bkt[pos] = (unsigned short)b[j];
        }
    }
    __syncthreads();

    for (int i = t; i < cnt; i += 256) {
        int bb = bkt[i];
        rec_out[gbase[bb] + (i - lofs[bb])] = staged[i];
    }
}

// ---------------------------------------------------------------------------
// Fused fine-sort + segmented reduce. One block per 128-node bucket:
// chunked in-LDS counting sort (hist -> scan -> scatter), then wave-per-node
// register reduction: broadcast ds_read of records, 4 B/lane Sb gathers.
// Chunking makes any bucket size correct (never triggers >1 in practice).
// ---------------------------------------------------------------------------
__global__ __launch_bounds__(256) void sort_reduce(
        const unsigned* __restrict__ Sb,
        const int2* __restrict__ rec,
        const int* __restrict__ boffs,
        const float* __restrict__ bias,
        float* __restrict__ out) {
    __shared__ int2 srec[RCH];            // 48 KB
    __shared__ int h[128], cur[128], onode[129], sc[128];

    const int c    = blockIdx.x;
    const int t    = threadIdx.x;
    const int lane = t & 63;
    const int wave = t >> 6;
    const int beg  = boffs[c], end = boffs[c + 1];

    const float2 b2 = ((const float2*)bias)[lane];
    const int nChunks = ((end - beg + RCH - 1) / RCH > 1)
                        ? (end - beg + RCH - 1) / RCH : 1;

    for (int ch = 0; ch < nChunks; ++ch) {
        const int cb = beg + ch * RCH;
        const int ce = min(end, cb + RCH);

        if (t < 128) h[t] = 0;
        __syncthreads();                  // also fences previous chunk's reduce

        for (int i = cb + t; i < ce; i += 256)
            atomicAdd(&h[(rec[i].x >> 17) & 127], 1);
        __syncthreads();

        if (t < 128) sc[t] = h[t];
        __syncthreads();
        for (int off = 1; off < 128; off <<= 1) {
            int v = (t < 128 && t >= off) ? sc[t - off] : 0;
            __syncthreads();
            if (t < 128 && t >= off) sc[t] += v;
            __syncthreads();
        }
        if (t < 128) {
            int ex = (t == 0) ? 0 : sc[t - 1];
            onode[t] = ex; cur[t] = ex;
        }
        if (t == 127) onode[128] = sc[127];
        __syncthreads();

        for (int i = cb + t; i < ce; i += 256) {
            int2 q = rec[i];
            int dl = (q.x >> 17) & 127;
            int p = atomicAdd(&cur[dl], 1);
            srec[p] = make_int2(q.x & 0x1FFFF, q.y);
        }
        __syncthreads();

        // wave w reduces nodes w*32 .. w*32+31
        for (int g = 0; g < 32; ++g) {
            const int nl = wave * 32 + g;
            const int s0 = onode[nl], s1 = onode[nl + 1];
            float ax = 0.f, ay = 0.f, bx = 0.f, by = 0.f;
            int i = s0;
            for (; i + 1 < s1; i += 2) {          // 2-way ILP on gathers
                int2 r0 = srec[i], r1 = srec[i + 1];   // broadcast LDS reads
                unsigned p0 = Sb[(size_t)r0.x * 64 + lane];
                unsigned p1 = Sb[(size_t)r1.x * 64 + lane];
                float v0 = __int_as_float(r0.y), v1 = __int_as_float(r1.y);
                ax += v0 * __uint_as_float(p0 << 16);
                ay += v0 * __uint_as_float(p0 & 0xFFFF0000u);
                bx += v1 * __uint_as_float(p1 << 16);
                by += v1 * __uint_as_float(p1 & 0xFFFF0000u);
            }
            if (i < s1) {
                int2 r0 = srec[i];
                unsigned p0 = Sb[(size_t)r0.x * 64 + lane];
                float v0 = __int_as_float(r0.y);
                ax += v0 * __uint_as_float(p0 << 16);
                ay += v0 * __uint_as_float(p0 & 0xFFFF0000u);
            }
            const int node = c * 128 + nl;
            if (node < N_NODES) {
                float2* op = (float2*)(out + (size_t)node * D) + lane;
                float2 rv;
                if (ch == 0) rv = make_float2(ax + bx + b2.x, ay + by + b2.y);
                else {
                    float2 prev = *op;               // same wave wrote it (ch-1)
                    rv = make_float2(prev.x + ax + bx, prev.y + ay + by);
                }
                *op = rv;
            }
        }
    }
}

extern "C" void kernel_launch(void* const* d_in, const int* in_sizes, int n_in,
                              void* d_out, int out_size, void* d_ws, size_t ws_size,
                              hipStream_t stream) {
    const float* X    = (const float*)d_in[0];
    const int*   esrc = (const int*)  d_in[1];
    const int*   edst = (const int*)  d_in[2];
    const float* eval = (const float*)d_in[3];
    const float* W    = (const float*)d_in[4];
    const float* bias = (const float*)d_in[5];
    float* out = (float*)d_out;

    char* ws = (char*)d_ws;
    unsigned* SbU   = (unsigned*)(ws + OFF_SB);
    int2*     recs  = (int2*)    (ws + OFF_REC);
    int*      ghist = (int*)     (ws + OFF_GHIST);
    int*      boffs = (int*)     (ws + OFF_BOFFS);
    int*      gcur  = (int*)     (ws + OFF_GCUR);

    // S = X @ W (bf16, MFMA)
    gemm_mfma<<<782, 256, 0, stream>>>(X, W, SbU);

    // Coarse partition of edges into 128-node dst-buckets
    hipMemsetAsync(ghist, 0, K1C * 4, stream);
    hist_coarse<<<256, 256, 0, stream>>>(edst, ghist);
    scan_coarse<<<1, 256, 0, stream>>>(ghist, boffs, gcur);
    partition_edges<<<NCHUNK, 256, 0, stream>>>(esrc, edst, eval, gcur, recs);

    // Fused in-LDS fine sort + segmented reduce + bias
    sort_reduce<<<K1C, 256, 0, stream>>>(SbU, recs, boffs, bias, out);
}

// Round 6
// 440.905 us; speedup vs baseline: 1.5759x; 1.5759x over previous
//
#include <hip/hip_runtime.h>

#define N_NODES 100000
#define N_EDGES 3200000
#define D 128

#define K1C    782        // coarse buckets: bucket = dst >> 7 (128 nodes each)
#define CHUNK  2048       // edges per partition block
#define NCHUNK 1563       // ceil(N_EDGES / CHUNK)

// ---------------------------------------------------------------------------
// Workspace layout (bytes). Total ~77.3 MB; ws >= 78,000,512 proven round 2.
// ---------------------------------------------------------------------------
static const size_t OFF_SB    = 0;           // S bf16 packed: N*64 uints = 25.6 MB
static const size_t OFF_REC   = 25600000;    // E int2 (coarse-partitioned)
static const size_t OFF_SORT2 = 51200000;    // E int2 (fine-sorted)
static const size_t OFF_OFFS  = 76800000;    // N ints
static const size_t OFF_GHIST = 77200000;
static const size_t OFF_BOFFS = 77204096;
static const size_t OFF_GCUR  = 77208192;

typedef __attribute__((ext_vector_type(8))) short bf16x8;
typedef __attribute__((ext_vector_type(4))) float f32x4;

__device__ __forceinline__ unsigned short f2bf(float f) {
    unsigned u = __float_as_uint(f);
    return (unsigned short)((u + 0x7FFFu + ((u >> 16) & 1u)) >> 16);   // RNE
}

// ---------------------------------------------------------------------------
// S = X @ W via MFMA — verified in round 5 (absmax matched VALU-bf16 path).
// ---------------------------------------------------------------------------
__global__ __launch_bounds__(256) void gemm_mfma(const float* __restrict__ X,
                                                 const float* __restrict__ W,
                                                 unsigned* __restrict__ Sb) {
    __shared__ __align__(16) union {
        unsigned short wfrag[8][4][64][8];  // [ct][kt][lane][j] = 32 KB
        unsigned       stage[4][32][68];    // [wave][row][dword] = 34 KB
    } u;

    const int t    = threadIdx.x;
    const int lane = t & 63;
    const int wave = t >> 6;
    const int quad = lane >> 4;
    const int li   = lane & 15;
    const int rowBase = blockIdx.x * 128;

    // stage W[k][n] fp32 -> pre-packed bf16 B-fragments
    for (int i = t; i < D * D; i += 256) {
        int k = i >> 7, n = i & 127;
        u.wfrag[n >> 4][k >> 5][((k >> 3) & 3) * 16 + (n & 15)][k & 7] = f2bf(W[i]);
    }
    __syncthreads();

    f32x4 acc[2][8];
#pragma unroll
    for (int rt = 0; rt < 2; ++rt)
#pragma unroll
        for (int ct = 0; ct < 8; ++ct)
            acc[rt][ct] = (f32x4){0.f, 0.f, 0.f, 0.f};

#pragma unroll
    for (int kt = 0; kt < 4; ++kt) {
        bf16x8 a[2];
#pragma unroll
        for (int rt = 0; rt < 2; ++rt) {
            int row = rowBase + wave * 32 + rt * 16 + li;
            if (row >= N_NODES) row = N_NODES - 1;           // clamp; store masked
            const float* xp = X + (size_t)row * D + kt * 32 + quad * 8;
            float4 f0 = ((const float4*)xp)[0];
            float4 f1 = ((const float4*)xp)[1];
            bf16x8 av;
            av[0] = (short)f2bf(f0.x); av[1] = (short)f2bf(f0.y);
            av[2] = (short)f2bf(f0.z); av[3] = (short)f2bf(f0.w);
            av[4] = (short)f2bf(f1.x); av[5] = (short)f2bf(f1.y);
            av[6] = (short)f2bf(f1.z); av[7] = (short)f2bf(f1.w);
            a[rt] = av;
        }
#pragma unroll
        for (int ct = 0; ct < 8; ++ct) {
            bf16x8 b = *(const bf16x8*)&u.wfrag[ct][kt][lane][0];
            acc[0][ct] = __builtin_amdgcn_mfma_f32_16x16x32_bf16(a[0], b, acc[0][ct], 0, 0, 0);
            acc[1][ct] = __builtin_amdgcn_mfma_f32_16x16x32_bf16(a[1], b, acc[1][ct], 0, 0, 0);
        }
    }
    __syncthreads();

    unsigned short* sw = (unsigned short*)&u.stage[wave][0][0];  // 32 x 136 bf16
#pragma unroll
    for (int rt = 0; rt < 2; ++rt)
#pragma unroll
        for (int r = 0; r < 4; ++r) {
            int lrow = rt * 16 + quad * 4 + r;
#pragma unroll
            for (int ct = 0; ct < 8; ++ct)
                sw[lrow * 136 + ct * 16 + li] = f2bf(acc[rt][ct][r]);
        }
    for (int lrow = 0; lrow < 32; ++lrow) {
        int node = rowBase + wave * 32 + lrow;
        if (node < N_NODES)
            Sb[(size_t)node * 64 + lane] = ((unsigned*)sw)[lrow * 68 + lane];
    }
}

// ---------------------------------------------------------------------------
// Coarse histogram over K1C buckets
// ---------------------------------------------------------------------------
__global__ __launch_bounds__(256) void hist_coarse(const int* __restrict__ edst,
                                                   int* __restrict__ ghist) {
    __shared__ int h[K1C];
    for (int i = threadIdx.x; i < K1C; i += 256) h[i] = 0;
    __syncthreads();
    for (int e = blockIdx.x * 256 + threadIdx.x; e < N_EDGES; e += gridDim.x * 256)
        atomicAdd(&h[edst[e] >> 7], 1);
    __syncthreads();
    for (int i = threadIdx.x; i < K1C; i += 256)
        if (h[i]) atomicAdd(&ghist[i], h[i]);
}

__global__ __launch_bounds__(256) void scan_coarse(const int* __restrict__ ghist,
                                                   int* __restrict__ boffs,
                                                   int* __restrict__ gcursor) {
    __shared__ int sc[256];
    const int t = threadIdx.x;
    int v[4]; int s = 0;
#pragma unroll
    for (int j = 0; j < 4; ++j) {
        int idx = t * 4 + j;
        v[j] = (idx < K1C) ? ghist[idx] : 0;
        s += v[j];
    }
    sc[t] = s;
    __syncthreads();
    for (int off = 1; off < 256; off <<= 1) {
        int u = (t >= off) ? sc[t - off] : 0;
        __syncthreads();
        sc[t] += u;
        __syncthreads();
    }
    int run = (t == 0) ? 0 : sc[t - 1];
#pragma unroll
    for (int j = 0; j < 4; ++j) {
        int idx = t * 4 + j;
        if (idx < K1C) { boffs[idx] = run; gcursor[idx] = run; }
        run += v[j];
    }
    if (t == 255) boffs[K1C] = run;
}

// ---------------------------------------------------------------------------
// LDS-staged coarse partition (verified rounds 4/5).
// rec.x = src | (dst&127)<<17 ; rec.y = val bits.
// ---------------------------------------------------------------------------
__global__ __launch_bounds__(256) void partition_edges(
        const int* __restrict__ esrc,
        const int* __restrict__ edst,
        const float* __restrict__ eval,
        int* __restrict__ gcursor,
        int2* __restrict__ rec_out) {
    __shared__ int  hist[K1C];
    __shared__ int  lofs[K1C];
    __shared__ int  gbase[K1C];
    __shared__ int  sc[256];
    __shared__ int2 staged[CHUNK];
    __shared__ unsigned short bkt[CHUNK];

    const int t   = threadIdx.x;
    const int e0  = blockIdx.x * CHUNK;
    const int cnt = min(CHUNK, N_EDGES - e0);

    for (int i = t; i < K1C; i += 256) hist[i] = 0;
    __syncthreads();

    int b[8], r[8], sv[8]; float vv[8];
#pragma unroll
    for (int j = 0; j < 8; ++j) {
        int idx = t + j * 256;
        if (idx < cnt) {
            int e = e0 + idx;
            int d = edst[e];
            sv[j] = esrc[e] | ((d & 127) << 17);
            vv[j] = eval[e];
            b[j]  = d >> 7;
            r[j]  = atomicAdd(&hist[b[j]], 1);
        } else b[j] = -1;
    }
    __syncthreads();

    int hv[4]; int hs = 0;
#pragma unroll
    for (int j = 0; j < 4; ++j) {
        int idx = t * 4 + j;
        hv[j] = (idx < K1C) ? hist[idx] : 0;
        hs += hv[j];
    }
    sc[t] = hs;
    __syncthreads();
    for (int off = 1; off < 256; off <<= 1) {
        int u = (t >= off) ? sc[t - off] : 0;
        __syncthreads();
        sc[t] += u;
        __syncthreads();
    }
    int run = (t == 0) ? 0 : sc[t - 1];
#pragma unroll
    for (int j = 0; j < 4; ++j) {
        int idx = t * 4 + j;
        if (idx < K1C) {
            lofs[idx]  = run;
            gbase[idx] = hv[j] ? atomicAdd(&gcursor[idx], hv[j]) : 0;
        }
        run += hv[j];
    }
    __syncthreads();

#pragma unroll
    for (int j = 0; j < 8; ++j) {
        if (b[j] >= 0) {
            int pos = lofs[b[j]] + r[j];
            staged[pos] = make_int2(sv[j], __float_as_int(vv[j]));
            bkt[pos] = (unsigned short)b[j];
        }
    }
    __syncthreads();

    for (int i = t; i < cnt; i += 256) {
        int bb = bkt[i];
        rec_out[gbase[bb] + (i - lofs[bb])] = staged[i];
    }
}

// ---------------------------------------------------------------------------
// Fine sort within each coarse bucket (verified round 4). Scatter window is
// ~32 KB -> L2-resident. Emits per-node segment offsets.
// ---------------------------------------------------------------------------
__global__ __launch_bounds__(256) void fine_sort(
        const int2* __restrict__ rec,
        const int* __restrict__ boffs,
        int* __restrict__ offs,
        int2* __restrict__ sorted2) {
    __shared__ int h[128];
    __shared__ int cur[128];
    __shared__ int sc[256];

    const int c   = blockIdx.x;
    const int t   = threadIdx.x;
    const int beg = boffs[c];
    const int end = boffs[c + 1];

    if (t < 128) h[t] = 0;
    __syncthreads();

    for (int i = beg + t; i < end; i += 256)
        atomicAdd(&h[(rec[i].x >> 17) & 127], 1);
    __syncthreads();

    sc[t] = (t < 128) ? h[t] : 0;
    __syncthreads();
    for (int off = 1; off < 128; off <<= 1) {
        int u = (t >= off) ? sc[t - off] : 0;
        __syncthreads();
        sc[t] += u;
        __syncthreads();
    }
    if (t < 128) {
        int excl = (t == 0) ? 0 : sc[t - 1];
        int node = c * 128 + t;
        if (node < N_NODES) offs[node] = beg + excl;
        cur[t] = beg + excl;
    }
    __syncthreads();

    for (int i = beg + t; i < end; i += 256) {
        int2 q = rec[i];
        int dl = (q.x >> 17) & 127;
        int p = atomicAdd(&cur[dl], 1);
        sorted2[p] = make_int2(q.x & 0x1FFFF, q.y);
    }
}

// ---------------------------------------------------------------------------
// Wave-per-node segmented reduce, half-wave record pairing:
// lanes 0-31 gather record 2j, lanes 32-63 gather record 2j+1 (uint2 =
// 8 B/lane = feats 4hl..4hl+3). 4 pairs unrolled -> 4 outstanding 512 B
// gathers/wave. Halves combined via shfl(lane^32); lanes 0-31 store float4.
// Tail records are zero-padded (val=0) so no masking needed in the loop.
// ---------------------------------------------------------------------------
__global__ __launch_bounds__(256) void reduce_segments(
        const unsigned* __restrict__ Sb,
        const int2* __restrict__ sorted,
        const int* __restrict__ offs,
        const float* __restrict__ bias,
        float* __restrict__ out) {
    const int lane = threadIdx.x & 63;
    const int node = (blockIdx.x * 256 + threadIdx.x) >> 6;
    if (node >= N_NODES) return;

    const int half = lane >> 5;        // which record of the pair
    const int hl   = lane & 31;        // lane within half: feats 4hl..4hl+3

    const int beg = offs[node];
    const int end = (node == N_NODES - 1) ? N_EDGES : offs[node + 1];

    float a0 = 0.f, a1 = 0.f, a2 = 0.f, a3 = 0.f;

    for (int base = beg; base < end; base += 64) {
        const int m = min(64, end - base);
        int2 rec = make_int2(0, 0);
        if (base + lane < end) rec = sorted[base + lane];
        const int pairs = (m + 1) >> 1;

        int j = 0;
        for (; j + 4 <= pairs; j += 4) {
#pragma unroll
            for (int q = 0; q < 4; ++q) {
                // separate address/load from FMA for scheduling: do loads first
            }
            int i0 = 2 * (j + 0) + half, i1 = 2 * (j + 1) + half;
            int i2 = 2 * (j + 2) + half, i3 = 2 * (j + 3) + half;
            int s0 = __shfl(rec.x, i0); int s1 = __shfl(rec.x, i1);
            int s2 = __shfl(rec.x, i2); int s3 = __shfl(rec.x, i3);
            float v0 = __int_as_float(__shfl(rec.y, i0));
            float v1 = __int_as_float(__shfl(rec.y, i1));
            float v2 = __int_as_float(__shfl(rec.y, i2));
            float v3 = __int_as_float(__shfl(rec.y, i3));
            uint2 p0 = ((const uint2*)(Sb + (size_t)s0 * 64))[hl];
            uint2 p1 = ((const uint2*)(Sb + (size_t)s1 * 64))[hl];
            uint2 p2 = ((const uint2*)(Sb + (size_t)s2 * 64))[hl];
            uint2 p3 = ((const uint2*)(Sb + (size_t)s3 * 64))[hl];
            a0 += v0 * __uint_as_float(p0.x << 16);
            a1 += v0 * __uint_as_float(p0.x & 0xFFFF0000u);
            a2 += v0 * __uint_as_float(p0.y << 16);
            a3 += v0 * __uint_as_float(p0.y & 0xFFFF0000u);
            a0 += v1 * __uint_as_float(p1.x << 16);
            a1 += v1 * __uint_as_float(p1.x & 0xFFFF0000u);
            a2 += v1 * __uint_as_float(p1.y << 16);
            a3 += v1 * __uint_as_float(p1.y & 0xFFFF0000u);
            a0 += v2 * __uint_as_float(p2.x << 16);
            a1 += v2 * __uint_as_float(p2.x & 0xFFFF0000u);
            a2 += v2 * __uint_as_float(p2.y << 16);
            a3 += v2 * __uint_as_float(p2.y & 0xFFFF0000u);
            a0 += v3 * __uint_as_float(p3.x << 16);
            a1 += v3 * __uint_as_float(p3.x & 0xFFFF0000u);
            a2 += v3 * __uint_as_float(p3.y << 16);
            a3 += v3 * __uint_as_float(p3.y & 0xFFFF0000u);
        }
        for (; j < pairs; ++j) {
            int i0 = 2 * j + half;
            int s0 = __shfl(rec.x, i0);
            float v0 = __int_as_float(__shfl(rec.y, i0));
            uint2 p0 = ((const uint2*)(Sb + (size_t)s0 * 64))[hl];
            a0 += v0 * __uint_as_float(p0.x << 16);
            a1 += v0 * __uint_as_float(p0.x & 0xFFFF0000u);
            a2 += v0 * __uint_as_float(p0.y << 16);
            a3 += v0 * __uint_as_float(p0.y & 0xFFFF0000u);
        }
    }

    // combine the two halves (feats 4hl..4hl+3 live in lanes hl and hl+32)
    a0 += __shfl(a0, lane ^ 32);
    a1 += __shfl(a1, lane ^ 32);
    a2 += __shfl(a2, lane ^ 32);
    a3 += __shfl(a3, lane ^ 32);

    if (half == 0) {
        float4 b4 = ((const float4*)bias)[hl];
        float4 r4 = make_float4(a0 + b4.x, a1 + b4.y, a2 + b4.z, a3 + b4.w);
        ((float4*)(out + (size_t)node * D))[hl] = r4;
    }
}

extern "C" void kernel_launch(void* const* d_in, const int* in_sizes, int n_in,
                              void* d_out, int out_size, void* d_ws, size_t ws_size,
                              hipStream_t stream) {
    const float* X    = (const float*)d_in[0];
    const int*   esrc = (const int*)  d_in[1];
    const int*   edst = (const int*)  d_in[2];
    const float* eval = (const float*)d_in[3];
    const float* W    = (const float*)d_in[4];
    const float* bias = (const float*)d_in[5];
    float* out = (float*)d_out;

    char* ws = (char*)d_ws;
    unsigned* SbU   = (unsigned*)(ws + OFF_SB);
    int2*     recs  = (int2*)    (ws + OFF_REC);
    int2*     srt2  = (int2*)    (ws + OFF_SORT2);
    int*      offs  = (int*)     (ws + OFF_OFFS);
    int*      ghist = (int*)     (ws + OFF_GHIST);
    int*      boffs = (int*)     (ws + OFF_BOFFS);
    int*      gcur  = (int*)     (ws + OFF_GCUR);

    // S = X @ W (bf16, MFMA)
    gemm_mfma<<<782, 256, 0, stream>>>(X, W, SbU);

    // Two-level counting sort of edges by dst (all scatters L2-resident)
    hipMemsetAsync(ghist, 0, K1C * 4, stream);
    hist_coarse<<<256, 256, 0, stream>>>(edst, ghist);
    scan_coarse<<<1, 256, 0, stream>>>(ghist, boffs, gcur);
    partition_edges<<<NCHUNK, 256, 0, stream>>>(esrc, edst, eval, gcur, recs);
    fine_sort<<<K1C, 256, 0, stream>>>(recs, boffs, offs, srt2);

    // Segmented reduce: out[n] = bias + sum val * S[src]
    reduce_segments<<<(N_NODES + 3) / 4, 256, 0, stream>>>(
        SbU, srt2, offs, bias, out);
}